// Round 1
// baseline (125.431 us; speedup 1.0000x reference)
//
#include <hip/hip_runtime.h>

// Problem constants (fixed by the reference).
#define NS 4
#define NA 8192
#define NC 8
#define THREADS 256
#define JSLOTS 4
#define JPB (THREADS * JSLOTS)   // 1024 j-atoms per block
#define TI 512                   // i-atoms per block (LDS tile)
#define NJB (NA / JPB)           // 8
#define NIB (NA / TI)            // 16

// ws layout: [0, NA) chain ids (int), [NA, NA+NS*NC*NC) global counts (int)

__global__ __launch_bounds__(THREADS)
void setup_kernel(const int* __restrict__ asym, const int* __restrict__ a2t,
                  int* __restrict__ chain, int* __restrict__ counts) {
  int i = blockIdx.x * THREADS + threadIdx.x;
  if (i < NA) chain[i] = asym[a2t[i]];
  // NS*NC*NC == 256 == THREADS: block 0 zeroes the count accumulators
  if (blockIdx.x == 0) counts[threadIdx.x] = 0;
}

__global__ __launch_bounds__(THREADS)
void pair_kernel(const float* __restrict__ coords, const int* __restrict__ chain,
                 int* __restrict__ counts) {
  __shared__ float4 tile[TI];     // (2x, 2y, 2z, sq - thr^2) per i-atom
  __shared__ int tchain[TI];
  __shared__ int red[NC * NC];

  const int tid = threadIdx.x;
  const int ib = blockIdx.x, jb = blockIdx.y, s = blockIdx.z;
  if (tid < NC * NC) red[tid] = 0;

  const float* __restrict__ base = coords + (size_t)s * NA * 3;
  const float THR2 = (float)(1.1 * 1.1);

  // Per-thread j-atoms (4 slots, stride 256)
  float xj[JSLOTS], yj[JSLOTS], zj[JSLOTS], tj[JSLOTS];
  int bj[JSLOTS];
#pragma unroll
  for (int u = 0; u < JSLOTS; ++u) {
    int j = jb * JPB + u * THREADS + tid;
    float x = base[3 * j + 0], y = base[3 * j + 1], z = base[3 * j + 2];
    xj[u] = x; yj[u] = y; zj[u] = z;
    tj[u] = x * x + y * y + z * z;
    bj[u] = chain[j];
  }

  // Stage i-tile into LDS
  for (int k = tid; k < TI; k += THREADS) {
    int i = ib * TI + k;
    float x = base[3 * i + 0], y = base[3 * i + 1], z = base[3 * i + 2];
    float sq = x * x + y * y + z * z;
    tile[k] = make_float4(2.0f * x, 2.0f * y, 2.0f * z, sq - THR2);
    tchain[k] = chain[i];
  }
  __syncthreads();

  int cnt[JSLOTS][NC];
#pragma unroll
  for (int u = 0; u < JSLOTS; ++u)
#pragma unroll
    for (int a = 0; a < NC; ++a) cnt[u][a] = 0;

  // clash  <=>  d2 < thr2  <=>  2*dot - (sq_i - thr2) > sq_j
#define PAIR_STEP(A, KK)                                                        \
  {                                                                             \
    float4 ci = tile[KK];                                                       \
    float d0 = fmaf(ci.x, xj[0], fmaf(ci.y, yj[0], fmaf(ci.z, zj[0], -ci.w)));  \
    float d1 = fmaf(ci.x, xj[1], fmaf(ci.y, yj[1], fmaf(ci.z, zj[1], -ci.w)));  \
    float d2 = fmaf(ci.x, xj[2], fmaf(ci.y, yj[2], fmaf(ci.z, zj[2], -ci.w)));  \
    float d3 = fmaf(ci.x, xj[3], fmaf(ci.y, yj[3], fmaf(ci.z, zj[3], -ci.w)));  \
    cnt[0][A] += (d0 > tj[0]);                                                  \
    cnt[1][A] += (d1 > tj[1]);                                                  \
    cnt[2][A] += (d2 > tj[2]);                                                  \
    cnt[3][A] += (d3 > tj[3]);                                                  \
  }

  // Inner loop: 64-i sub-blocks; chain_i is wave-uniform per iteration.
  for (int k0 = 0; k0 < TI; k0 += 64) {
    int my_a = tchain[k0 + (tid & 63)];
    int a0 = __builtin_amdgcn_readfirstlane(my_a);
    if (__all(my_a == a0)) {
      switch (a0) {
#define RUN64(A)                                        \
  case A: {                                             \
    _Pragma("unroll 8")                                 \
    for (int t = 0; t < 64; ++t) PAIR_STEP(A, k0 + t)   \
  } break;
        RUN64(0) RUN64(1) RUN64(2) RUN64(3) RUN64(4) RUN64(5) RUN64(6) RUN64(7)
      }
    } else {
      // rare: mixed chains within the 64-i sub-block
      for (int t = 0; t < 64; ++t) {
        int a = __builtin_amdgcn_readfirstlane(tchain[k0 + t]);
        switch (a) {
#define ONE(A) case A: PAIR_STEP(A, k0 + t) break;
          ONE(0) ONE(1) ONE(2) ONE(3) ONE(4) ONE(5) ONE(6) ONE(7)
        }
      }
    }
  }

  // Block-level reduction into red[a][b], then one global atomic per entry.
  int b0 = bj[0];
  bool slots_same = (bj[1] == b0) && (bj[2] == b0) && (bj[3] == b0);
  int uni = __all(slots_same && (b0 == __builtin_amdgcn_readfirstlane(b0)));
  if (uni) {
#pragma unroll
    for (int a = 0; a < NC; ++a) {
      int v = cnt[0][a] + cnt[1][a] + cnt[2][a] + cnt[3][a];
#pragma unroll
      for (int m = 32; m >= 1; m >>= 1) v += __shfl_xor(v, m, 64);
      if ((tid & 63) == 0) atomicAdd(&red[a * NC + b0], v);
    }
  } else {
#pragma unroll
    for (int u = 0; u < JSLOTS; ++u)
#pragma unroll
      for (int a = 0; a < NC; ++a)
        if (cnt[u][a]) atomicAdd(&red[a * NC + bj[u]], cnt[u][a]);
  }
  __syncthreads();
  if (tid < NC * NC) {
    int v = red[tid];
    if (v) atomicAdd(&counts[s * NC * NC + tid], v);
  }
}

__global__ __launch_bounds__(THREADS)
void finalize_kernel(const int* __restrict__ chain, const int* __restrict__ counts,
                     float* __restrict__ out) {
  __shared__ int hist[NC];
  int tid = threadIdx.x;
  if (tid < NC) hist[tid] = 0;
  __syncthreads();
  for (int i = tid; i < NA; i += THREADS) atomicAdd(&hist[chain[i]], 1);
  __syncthreads();

  // tid = s*64 + a*8 + b  (256 threads cover all entries)
  int ab = tid & 63, a = ab >> 3, b = ab & 7;
  int c = counts[tid];
  float total = (a == b) ? 0.0f : (float)c;
  float minn = (float)min(hist[a], hist[b]);
  float rel = total / minn;
  out[tid] = ((total > 100.0f) || (rel > 0.5f)) ? 1.0f : 0.0f;
  out[256 + 2 * tid + 0] = total;
  out[256 + 2 * tid + 1] = rel;
}

extern "C" void kernel_launch(void* const* d_in, const int* in_sizes, int n_in,
                              void* d_out, int out_size, void* d_ws, size_t ws_size,
                              hipStream_t stream) {
  const float* coords = (const float*)d_in[0];  // [4, 8192, 3] f32
  const int* asym = (const int*)d_in[1];        // [1024] i32
  const int* a2t = (const int*)d_in[2];         // [8192] i32
  float* out = (float*)d_out;                   // 256 flags + 512 details

  int* chain = (int*)d_ws;        // [8192]
  int* counts = chain + NA;       // [4*8*8]

  setup_kernel<<<dim3(NA / THREADS), THREADS, 0, stream>>>(asym, a2t, chain, counts);
  pair_kernel<<<dim3(NIB, NJB, NS), THREADS, 0, stream>>>(coords, chain, counts);
  finalize_kernel<<<1, THREADS, 0, stream>>>(chain, counts, out);
}